// Round 14
// baseline (249.877 us; speedup 1.0000x reference)
//
#include <hip/hip_runtime.h>

#define TQ_D   1024
#define TQ_KC  16
#define BK     16
#define MERGE_K 512          // OpenBLAS KC-panel boundary (proven R9)
#define NT_HALF (MERGE_K / BK)   // 32 k-tiles per panel

// ---- shared tile shape (proven at FMA roofline by K2/R10) ----
#define BM     128
#define BN     64
#define LDA    (BM + 4)      // 132
#define LDB    (BN + 4)      // 68

// ---------------------------------------------------------------------------
// K1 split into two half-K GEMMs to keep ONE 32-reg accumulator per kernel
// (the dual-panel accumulator caused R10 spill / R11 LDS squeeze / R13
// LDS-BW-bound small tile). Realization is EXACTLY R9's: serial ascending-k
// f32 FMA chain per element within each 512-wide panel; panels merged with a
// single f32 add (K1a's f32 store/load round-trip is bit-exact); literal f32
// argmin (first strict min).
// PHASE 0 (K1a): y1 = x[:, 0:512] @ Pi[:, 0:512]^T -> raw f32 into Ybuf.
// PHASE 1 (K1b): acc = x[:, 512:1024] @ Pi[:, 512:1024]^T; y = Ybuf + acc;
//                argmin -> overwrite Ybuf with index (as float).
// ---------------------------------------------------------------------------
template <int PHASE>
__global__ __launch_bounds__(256, 2)
void tq_panel(const float* __restrict__ X,
              const float* __restrict__ Pi,
              const float* __restrict__ Cent,
              float* __restrict__ Ybuf)
{
    __shared__ float As[BK][LDA];
    __shared__ float Bs[BK][LDB];

    const int tid = threadIdx.x;
    const int m0 = blockIdx.y * BM;
    const int n0 = blockIdx.x * BN;
    const int tx = tid & 15;
    const int ty = tid >> 4;

    const int rr = tid >> 2;   // staging row 0..63
    const int cc = tid & 3;    // staging k-quad

    const int k0 = PHASE * MERGE_K;
    const float* aPtr = X  + (size_t)(m0 + rr) * TQ_D + k0 + (cc << 2);
    const float* bPtr = Pi + (size_t)(n0 + rr) * TQ_D + k0 + (cc << 2);

    float acc[2][4][4];
#pragma unroll
    for (int r = 0; r < 2; ++r)
#pragma unroll
        for (int i = 0; i < 4; ++i)
#pragma unroll
            for (int j = 0; j < 4; ++j) acc[r][i][j] = 0.0f;

    // stage tile 0
    float4 va0 = *(const float4*)(aPtr);
    float4 va1 = *(const float4*)(aPtr + (size_t)64 * TQ_D);
    float4 vb0 = *(const float4*)(bPtr);
#pragma unroll
    for (int q = 0; q < 4; ++q) {
        As[(cc << 2) + q][rr]      = ((const float*)&va0)[q];
        As[(cc << 2) + q][rr + 64] = ((const float*)&va1)[q];
        Bs[(cc << 2) + q][rr]      = ((const float*)&vb0)[q];
    }
    __syncthreads();

    for (int kt = 0; kt < NT_HALF; ++kt) {
        const bool more = (kt + 1) < NT_HALF;
        if (more) {
            const float* ap = aPtr + (kt + 1) * BK;
            const float* bp = bPtr + (kt + 1) * BK;
            va0 = *(const float4*)(ap);
            va1 = *(const float4*)(ap + (size_t)64 * TQ_D);
            vb0 = *(const float4*)(bp);
        }
#pragma unroll
        for (int k = 0; k < BK; ++k) {
            const float4 a0 = *(const float4*)&As[k][ty << 2];
            const float4 a1 = *(const float4*)&As[k][64 + (ty << 2)];
            const float4 b0 = *(const float4*)&Bs[k][tx << 2];
            const float a0v[4] = {a0.x, a0.y, a0.z, a0.w};
            const float a1v[4] = {a1.x, a1.y, a1.z, a1.w};
            const float bv[4]  = {b0.x, b0.y, b0.z, b0.w};
#pragma unroll
            for (int i = 0; i < 4; ++i)
#pragma unroll
                for (int j = 0; j < 4; ++j) {
                    acc[0][i][j] = fmaf(a0v[i], bv[j], acc[0][i][j]);
                    acc[1][i][j] = fmaf(a1v[i], bv[j], acc[1][i][j]);
                }
        }
        if (more) {
            __syncthreads();
#pragma unroll
            for (int q = 0; q < 4; ++q) {
                As[(cc << 2) + q][rr]      = ((const float*)&va0)[q];
                As[(cc << 2) + q][rr + 64] = ((const float*)&va1)[q];
                Bs[(cc << 2) + q][rr]      = ((const float*)&vb0)[q];
            }
            __syncthreads();
        }
    }

    if constexpr (PHASE == 0) {
        // write raw panel-1 partials
#pragma unroll
        for (int r = 0; r < 2; ++r)
#pragma unroll
            for (int i = 0; i < 4; ++i) {
                const int m = m0 + (r << 6) + (ty << 2) + i;
                *(float4*)(Ybuf + (size_t)m * TQ_D + n0 + (tx << 2)) =
                    make_float4(acc[r][i][0], acc[r][i][1], acc[r][i][2], acc[r][i][3]);
            }
    } else {
        float c[TQ_KC];
#pragma unroll
        for (int q = 0; q < TQ_KC; ++q) c[q] = Cent[q];

#pragma unroll
        for (int r = 0; r < 2; ++r)
#pragma unroll
            for (int i = 0; i < 4; ++i) {
                const int m = m0 + (r << 6) + (ty << 2) + i;
                float* p = Ybuf + (size_t)m * TQ_D + n0 + (tx << 2);
                const float4 y1 = *(const float4*)p;
                const float y1v[4] = {y1.x, y1.y, y1.z, y1.w};
                float o[4];
#pragma unroll
                for (int j = 0; j < 4; ++j) {
                    const float y = y1v[j] + acc[r][i][j];   // exact R9 panel merge
                    int best = 0;
                    float bd = fabsf(y - c[0]);
#pragma unroll
                    for (int q = 1; q < TQ_KC; ++q) {
                        const float d = fabsf(y - c[q]);
                        if (d < bd) { bd = d; best = q; }
                    }
                    o[j] = (float)best;
                }
                *(float4*)p = make_float4(o[0], o[1], o[2], o[3]);
            }
    }
}

// ---------------------------------------------------------------------------
// Kernel 2: x_hat = dequant(idx) @ Pi (NN GEMM, f32) — UNCHANGED (at the
// f32 vector-FMA roofline, ~54us floor).
// ---------------------------------------------------------------------------
__global__ __launch_bounds__(256, 2)
void tq_dequant_unrotate(const float* __restrict__ IdxF,
                         const float* __restrict__ Pi,
                         const float* __restrict__ Cent,
                         float* __restrict__ Xhat)
{
    __shared__ float As[BK][LDA];
    __shared__ float Bs[BK][LDB];
    __shared__ float cs[TQ_KC];

    const int tid = threadIdx.x;
    const int m0 = blockIdx.y * BM;
    const int n0 = blockIdx.x * BN;
    const int tx = tid & 15;
    const int ty = tid >> 4;

    const int rr = tid >> 2;
    const int cc = tid & 3;
    const int kr = tid >> 4;
    const int cq = tid & 15;

    const float* aPtr = IdxF + (size_t)(m0 + rr) * TQ_D + (cc << 2);
    const float* pPtr = Pi + (size_t)kr * TQ_D + n0 + (cq << 2);

    if (tid < TQ_KC) cs[tid] = Cent[tid];

    float acc[2][4][4];
#pragma unroll
    for (int r = 0; r < 2; ++r)
#pragma unroll
        for (int i = 0; i < 4; ++i)
#pragma unroll
            for (int j = 0; j < 4; ++j) acc[r][i][j] = 0.0f;

    float4 va0 = *(const float4*)(aPtr);
    float4 va1 = *(const float4*)(aPtr + (size_t)64 * TQ_D);
    float4 vb0 = *(const float4*)(pPtr);
    __syncthreads();   // cs[] ready
#pragma unroll
    for (int q = 0; q < 4; ++q) {
        As[(cc << 2) + q][rr]      = cs[((int)((const float*)&va0)[q]) & 15];
        As[(cc << 2) + q][rr + 64] = cs[((int)((const float*)&va1)[q]) & 15];
    }
    *(float4*)&Bs[kr][cq << 2] = vb0;
    __syncthreads();

    for (int kt = 0; kt < TQ_D / BK; ++kt) {
        const bool more = (kt + 1) < TQ_D / BK;
        if (more) {
            const float* ap = aPtr + (kt + 1) * BK;
            const float* bp = pPtr + (size_t)(kt + 1) * BK * TQ_D;
            va0 = *(const float4*)(ap);
            va1 = *(const float4*)(ap + (size_t)64 * TQ_D);
            vb0 = *(const float4*)(bp);
        }
#pragma unroll
        for (int k = 0; k < BK; ++k) {
            const float4 a0 = *(const float4*)&As[k][ty << 2];
            const float4 a1 = *(const float4*)&As[k][64 + (ty << 2)];
            const float4 b0 = *(const float4*)&Bs[k][tx << 2];
            const float a0v[4] = {a0.x, a0.y, a0.z, a0.w};
            const float a1v[4] = {a1.x, a1.y, a1.z, a1.w};
            const float bv[4]  = {b0.x, b0.y, b0.z, b0.w};
#pragma unroll
            for (int i = 0; i < 4; ++i)
#pragma unroll
                for (int j = 0; j < 4; ++j) {
                    acc[0][i][j] = fmaf(a0v[i], bv[j], acc[0][i][j]);
                    acc[1][i][j] = fmaf(a1v[i], bv[j], acc[1][i][j]);
                }
        }
        if (more) {
            __syncthreads();
#pragma unroll
            for (int q = 0; q < 4; ++q) {
                As[(cc << 2) + q][rr]      = cs[((int)((const float*)&va0)[q]) & 15];
                As[(cc << 2) + q][rr + 64] = cs[((int)((const float*)&va1)[q]) & 15];
            }
            *(float4*)&Bs[kr][cq << 2] = vb0;
            __syncthreads();
        }
    }

#pragma unroll
    for (int r = 0; r < 2; ++r)
#pragma unroll
        for (int i = 0; i < 4; ++i) {
            const int m = m0 + (r << 6) + (ty << 2) + i;
            *(float4*)(Xhat + (size_t)m * TQ_D + n0 + (tx << 2)) =
                make_float4(acc[r][i][0], acc[r][i][1], acc[r][i][2], acc[r][i][3]);
        }
}

// ---------------------------------------------------------------------------
extern "C" void kernel_launch(void* const* d_in, const int* in_sizes, int n_in,
                              void* d_out, int out_size, void* d_ws, size_t ws_size,
                              hipStream_t stream)
{
    const float* x    = (const float*)d_in[0];   // [N, 1024]
    const float* Pi   = (const float*)d_in[1];   // [1024, 1024]
    const float* cent = (const float*)d_in[2];   // [16]
    float* out = (float*)d_out;

    const int ND = in_sizes[0];      // N * 1024
    const int N  = ND / TQ_D;        // 4096

    float* xhat = out;               // output 0: [N,1024] f32
    float* oidx = out + ND;          // output 1: indices as float
                                     // (also holds panel-1 partials between
                                     //  K1a and K1b — overwritten with idx)

    dim3 grid(TQ_D / BN, N / BM);    // (16, 32) = 512 blocks
    tq_panel<0><<<grid, 256, 0, stream>>>(x, Pi, cent, oidx);
    tq_panel<1><<<grid, 256, 0, stream>>>(x, Pi, cent, oidx);
    tq_dequant_unrotate<<<grid, 256, 0, stream>>>(oidx, Pi, cent, xhat);
}

// Round 15
// 187.638 us; speedup vs baseline: 1.3317x; 1.3317x over previous
//
#include <hip/hip_runtime.h>
#include <hip/hip_bf16.h>

#define TQ_D   1024
#define TQ_KC  16
#define BK     16
#define MERGE_K 512          // OpenBLAS KC-panel boundary (proven R9)
#define NT_HALF (MERGE_K / BK)   // 32 k-tiles per panel

// ---- K1 tile shape ----
#define BM     128
#define BN     64
#define LDA    (BM + 4)      // 132
#define LDB    (BN + 4)      // 68

// ---------------------------------------------------------------------------
// K1 split into two half-K GEMMs (proven R14). Realization EXACTLY R9's:
// serial ascending-k f32 FMA chain within each 512-wide panel; single f32
// panel-merge add (K1a f32 store/load round-trip is bit-exact); literal f32
// argmin (first strict min).
// ---------------------------------------------------------------------------
template <int PHASE>
__global__ __launch_bounds__(256, 2)
void tq_panel(const float* __restrict__ X,
              const float* __restrict__ Pi,
              const float* __restrict__ Cent,
              float* __restrict__ Ybuf)
{
    __shared__ float As[BK][LDA];
    __shared__ float Bs[BK][LDB];

    const int tid = threadIdx.x;
    const int m0 = blockIdx.y * BM;
    const int n0 = blockIdx.x * BN;
    const int tx = tid & 15;
    const int ty = tid >> 4;

    const int rr = tid >> 2;
    const int cc = tid & 3;

    const int k0 = PHASE * MERGE_K;
    const float* aPtr = X  + (size_t)(m0 + rr) * TQ_D + k0 + (cc << 2);
    const float* bPtr = Pi + (size_t)(n0 + rr) * TQ_D + k0 + (cc << 2);

    float acc[2][4][4];
#pragma unroll
    for (int r = 0; r < 2; ++r)
#pragma unroll
        for (int i = 0; i < 4; ++i)
#pragma unroll
            for (int j = 0; j < 4; ++j) acc[r][i][j] = 0.0f;

    float4 va0 = *(const float4*)(aPtr);
    float4 va1 = *(const float4*)(aPtr + (size_t)64 * TQ_D);
    float4 vb0 = *(const float4*)(bPtr);
#pragma unroll
    for (int q = 0; q < 4; ++q) {
        As[(cc << 2) + q][rr]      = ((const float*)&va0)[q];
        As[(cc << 2) + q][rr + 64] = ((const float*)&va1)[q];
        Bs[(cc << 2) + q][rr]      = ((const float*)&vb0)[q];
    }
    __syncthreads();

    for (int kt = 0; kt < NT_HALF; ++kt) {
        const bool more = (kt + 1) < NT_HALF;
        if (more) {
            const float* ap = aPtr + (kt + 1) * BK;
            const float* bp = bPtr + (kt + 1) * BK;
            va0 = *(const float4*)(ap);
            va1 = *(const float4*)(ap + (size_t)64 * TQ_D);
            vb0 = *(const float4*)(bp);
        }
#pragma unroll
        for (int k = 0; k < BK; ++k) {
            const float4 a0 = *(const float4*)&As[k][ty << 2];
            const float4 a1 = *(const float4*)&As[k][64 + (ty << 2)];
            const float4 b0 = *(const float4*)&Bs[k][tx << 2];
            const float a0v[4] = {a0.x, a0.y, a0.z, a0.w};
            const float a1v[4] = {a1.x, a1.y, a1.z, a1.w};
            const float bv[4]  = {b0.x, b0.y, b0.z, b0.w};
#pragma unroll
            for (int i = 0; i < 4; ++i)
#pragma unroll
                for (int j = 0; j < 4; ++j) {
                    acc[0][i][j] = fmaf(a0v[i], bv[j], acc[0][i][j]);
                    acc[1][i][j] = fmaf(a1v[i], bv[j], acc[1][i][j]);
                }
        }
        if (more) {
            __syncthreads();
#pragma unroll
            for (int q = 0; q < 4; ++q) {
                As[(cc << 2) + q][rr]      = ((const float*)&va0)[q];
                As[(cc << 2) + q][rr + 64] = ((const float*)&va1)[q];
                Bs[(cc << 2) + q][rr]      = ((const float*)&vb0)[q];
            }
            __syncthreads();
        }
    }

    if constexpr (PHASE == 0) {
#pragma unroll
        for (int r = 0; r < 2; ++r)
#pragma unroll
            for (int i = 0; i < 4; ++i) {
                const int m = m0 + (r << 6) + (ty << 2) + i;
                *(float4*)(Ybuf + (size_t)m * TQ_D + n0 + (tx << 2)) =
                    make_float4(acc[r][i][0], acc[r][i][1], acc[r][i][2], acc[r][i][3]);
            }
    } else {
        float c[TQ_KC];
#pragma unroll
        for (int q = 0; q < TQ_KC; ++q) c[q] = Cent[q];

#pragma unroll
        for (int r = 0; r < 2; ++r)
#pragma unroll
            for (int i = 0; i < 4; ++i) {
                const int m = m0 + (r << 6) + (ty << 2) + i;
                float* p = Ybuf + (size_t)m * TQ_D + n0 + (tx << 2);
                const float4 y1 = *(const float4*)p;
                const float y1v[4] = {y1.x, y1.y, y1.z, y1.w};
                float o[4];
#pragma unroll
                for (int j = 0; j < 4; ++j) {
                    const float y = y1v[j] + acc[r][i][j];   // exact R9 panel merge
                    int best = 0;
                    float bd = fabsf(y - c[0]);
#pragma unroll
                    for (int q = 1; q < TQ_KC; ++q) {
                        const float d = fabsf(y - c[q]);
                        if (d < bd) { bd = d; best = q; }
                    }
                    o[j] = (float)best;
                }
                *(float4*)p = make_float4(o[0], o[1], o[2], o[3]);
            }
    }
}

// ---------------------------------------------------------------------------
// Kernel 2 (NEW, MFMA): x_hat = dequant(idx) @ Pi in bf16 MFMA, f32 accum.
// Output 0 tolerance is 0.3 in bf16 — bf16 input rounding (~0.05 absmax) is
// far inside it; indices (exact path) are untouched.
// 128x128 tile, BK=32, 4 waves in 2x2 (64x64/wave), 4x4 16x16 subtiles/wave.
// LDS: Ys[128][40] bf16 (y_hat, dequant at staging via bf16 LUT),
//      Ps[128][40] bf16 (Ps[n][k] = Pi[k0+k][n0+n] — transposed at staging).
// Fragments are single ds_read_b128, ~2-way banked (free).
// C/D layout (m89-verified): col = lane&15, row = (lane>>4)*4 + reg.
// ---------------------------------------------------------------------------
typedef __attribute__((ext_vector_type(8))) short bf16x8;
typedef __attribute__((ext_vector_type(4))) float f32x4;

__device__ __forceinline__ unsigned short f2bf(float f) {
    union { __hip_bfloat16 h; unsigned short s; } u;
    u.h = __float2bfloat16(f);
    return u.s;
}

__global__ __launch_bounds__(256)
void tq_dq_mfma(const float* __restrict__ IdxF,
                const float* __restrict__ Pi,
                const float* __restrict__ Cent,
                float* __restrict__ Xhat)
{
    __shared__ unsigned short Ys[128][40];   // 80B rows, 16B-aligned
    __shared__ unsigned short Ps[128][40];
    __shared__ unsigned short csb[TQ_KC];    // bf16 centroid LUT

    const int tid  = threadIdx.x;
    const int lane = tid & 63;
    const int wv   = tid >> 6;
    const int m0 = blockIdx.y * 128;
    const int n0 = blockIdx.x * 128;
    const int wr = (wv >> 1) * 64;     // wave row origin
    const int wc = (wv & 1) * 64;      // wave col origin
    const int l15 = lane & 15;
    const int k8  = (lane >> 4) * 8;

    // staging coords
    const int arow = tid >> 1;             // 0..127
    const int acol = (tid & 1) * 16;       // 0 or 16
    const int bn   = tid & 127;            // 0..127 (col of Pi)
    const int bkq  = (tid >> 7) * 16;      // 0 or 16

    const float* aP = IdxF + (size_t)(m0 + arow) * TQ_D + acol;
    const float* bP = Pi + (size_t)bkq * TQ_D + n0 + bn;

    if (tid < TQ_KC) csb[tid] = f2bf(Cent[tid]);

    f32x4 acc[4][4];
#pragma unroll
    for (int i = 0; i < 4; ++i)
#pragma unroll
        for (int j = 0; j < 4; ++j)
#pragma unroll
            for (int r = 0; r < 4; ++r) acc[i][j][r] = 0.0f;

    float4 va[4];
    float  vb[16];
    // prefetch tile 0
#pragma unroll
    for (int q = 0; q < 4; ++q) va[q] = *(const float4*)(aP + 4 * q);
#pragma unroll
    for (int k = 0; k < 16; ++k) vb[k] = bP[(size_t)k * TQ_D];

    __syncthreads();   // csb ready

    // stage tile 0
#pragma unroll
    for (int q = 0; q < 4; ++q) {
        ushort4 w;
        w.x = csb[(int)va[q].x & 15];
        w.y = csb[(int)va[q].y & 15];
        w.z = csb[(int)va[q].z & 15];
        w.w = csb[(int)va[q].w & 15];
        *(ushort4*)&Ys[arow][acol + 4 * q] = w;
    }
#pragma unroll
    for (int k = 0; k < 16; ++k) Ps[bn][bkq + k] = f2bf(vb[k]);
    __syncthreads();

    for (int kt = 0; kt < 32; ++kt) {
        const bool more = (kt + 1) < 32;
        if (more) {
            const float* ap = aP + (kt + 1) * 32;
            const float* bp = bP + (size_t)(kt + 1) * 32 * TQ_D;
#pragma unroll
            for (int q = 0; q < 4; ++q) va[q] = *(const float4*)(ap + 4 * q);
#pragma unroll
            for (int k = 0; k < 16; ++k) vb[k] = bp[(size_t)k * TQ_D];
        }

        // fragments: single b128 each (A: row-major y; B: Ps[col][k]=Pi[k][col])
        bf16x8 af[4], bfr[4];
#pragma unroll
        for (int i = 0; i < 4; ++i)
            af[i] = *(const bf16x8*)&Ys[wr + i * 16 + l15][k8];
#pragma unroll
        for (int j = 0; j < 4; ++j)
            bfr[j] = *(const bf16x8*)&Ps[wc + j * 16 + l15][k8];

#pragma unroll
        for (int i = 0; i < 4; ++i)
#pragma unroll
            for (int j = 0; j < 4; ++j)
                acc[i][j] = __builtin_amdgcn_mfma_f32_16x16x32_bf16(
                    af[i], bfr[j], acc[i][j], 0, 0, 0);

        if (more) {
            __syncthreads();
#pragma unroll
            for (int q = 0; q < 4; ++q) {
                ushort4 w;
                w.x = csb[(int)va[q].x & 15];
                w.y = csb[(int)va[q].y & 15];
                w.z = csb[(int)va[q].z & 15];
                w.w = csb[(int)va[q].w & 15];
                *(ushort4*)&Ys[arow][acol + 4 * q] = w;
            }
#pragma unroll
            for (int k = 0; k < 16; ++k) Ps[bn][bkq + k] = f2bf(vb[k]);
            __syncthreads();
        }
    }

    // epilogue: C/D mapping col=lane&15, row=(lane>>4)*4+reg
#pragma unroll
    for (int i = 0; i < 4; ++i)
#pragma unroll
        for (int j = 0; j < 4; ++j)
#pragma unroll
            for (int r = 0; r < 4; ++r) {
                const int row = wr + i * 16 + (lane >> 4) * 4 + r;
                const int col = wc + j * 16 + l15;
                Xhat[(size_t)(m0 + row) * TQ_D + n0 + col] = acc[i][j][r];
            }
}

// ---------------------------------------------------------------------------
extern "C" void kernel_launch(void* const* d_in, const int* in_sizes, int n_in,
                              void* d_out, int out_size, void* d_ws, size_t ws_size,
                              hipStream_t stream)
{
    const float* x    = (const float*)d_in[0];   // [N, 1024]
    const float* Pi   = (const float*)d_in[1];   // [1024, 1024]
    const float* cent = (const float*)d_in[2];   // [16]
    float* out = (float*)d_out;

    const int ND = in_sizes[0];      // N * 1024
    const int N  = ND / TQ_D;        // 4096

    float* xhat = out;               // output 0: [N,1024] f32
    float* oidx = out + ND;          // output 1: indices as float
                                     // (holds panel-1 partials between K1a/K1b)

    dim3 grid1(TQ_D / BN, N / BM);   // (16, 32) = 512 blocks
    tq_panel<0><<<grid1, 256, 0, stream>>>(x, Pi, cent, oidx);
    tq_panel<1><<<grid1, 256, 0, stream>>>(x, Pi, cent, oidx);

    dim3 grid2(TQ_D / 128, N / 128); // (8, 32) = 256 blocks
    tq_dq_mfma<<<grid2, 256, 0, stream>>>(oidx, Pi, cent, xhat);
}